// Round 1
// baseline (898.583 us; speedup 1.0000x reference)
//
#include <hip/hip_runtime.h>
#include <math.h>

// ---- fixed problem sizes ----
#define NTOK 1024
#define DDIM 1024
#define HEADS 16
#define KVH 4
#define DH 64
#define BSZ 32
#define NSEL 8
#define WBLK 32            // NTOK / BSZ
#define GQ 4               // HEADS / KVH
#define CDIM 2048          // BSZ*DH
#define HIDN 2048
#define QKVD 1536          // (HEADS + 2*KVH)*DH
#define SCALE 0.125f       // DH^-0.5
#define NEGINF (-__builtin_inff())

// ---------------------------------------------------------------------------
// K1: RMSNorm  x[n,:] = inp[n,:] * rsqrt(mean(inp^2)+1e-6) * g
// ---------------------------------------------------------------------------
__global__ void rmsnorm_kernel(const float* __restrict__ inp, const float* __restrict__ g,
                               float* __restrict__ x) {
    int n = blockIdx.x;
    int t = threadIdx.x;            // 256 threads, one float4 each
    float4 v = ((const float4*)(inp + (size_t)n * DDIM))[t];
    float ss = v.x*v.x + v.y*v.y + v.z*v.z + v.w*v.w;
    for (int off = 32; off; off >>= 1) ss += __shfl_down(ss, off);
    __shared__ float red[4];
    if ((t & 63) == 0) red[t >> 6] = ss;
    __syncthreads();
    float tot = red[0] + red[1] + red[2] + red[3];
    float r = 1.f / sqrtf(tot * (1.f / DDIM) + 1e-6f);
    float4 gv = ((const float4*)g)[t];
    float4 o;
    o.x = v.x * r * gv.x; o.y = v.y * r * gv.y;
    o.z = v.z * r * gv.z; o.w = v.w * r * gv.w;
    ((float4*)(x + (size_t)n * DDIM))[t] = o;
}

// ---------------------------------------------------------------------------
// K2: generic tiled f32 GEMM  C = act(A[MxK] @ B[KxX] + bias)
// 64x64 tile, 256 threads, 4x4 per thread. M%64==0, X%64==0, K%16==0.
// blockIdx.z picks between two independent (A,B,bias,C) sets (batching).
// ACT: 0 none, 1 relu, 2 sigmoid
// ---------------------------------------------------------------------------
template<int ACT>
__global__ void gemm_kernel(const float* __restrict__ A0, const float* __restrict__ B0,
                            const float* __restrict__ b0, float* __restrict__ C0,
                            const float* __restrict__ A1, const float* __restrict__ B1,
                            const float* __restrict__ b1, float* __restrict__ C1,
                            int M, int K, int X) {
    const float* A    = blockIdx.z ? A1 : A0;
    const float* Bm   = blockIdx.z ? B1 : B0;
    const float* bias = blockIdx.z ? b1 : b0;
    float*       C    = blockIdx.z ? C1 : C0;
    __shared__ float As[16 * 65];   // [k][row], padded
    __shared__ float Bs[16 * 64];   // [k][col]
    int tid = threadIdx.x;
    int tx = tid & 15, ty = tid >> 4;          // 16x16 threads
    int row0 = blockIdx.y * 64, col0 = blockIdx.x * 64;
    float acc[4][4] = {};
    for (int k0 = 0; k0 < K; k0 += 16) {
#pragma unroll
        for (int i = 0; i < 4; ++i) {
            int idx = tid + i * 256;           // 0..1023
            int r = idx >> 4, c = idx & 15;
            As[c * 65 + r] = A[(size_t)(row0 + r) * K + k0 + c];
        }
#pragma unroll
        for (int i = 0; i < 4; ++i) {
            int idx = tid + i * 256;
            int r = idx >> 6, c = idx & 63;
            Bs[r * 64 + c] = Bm[(size_t)(k0 + r) * X + col0 + c];
        }
        __syncthreads();
#pragma unroll
        for (int kk = 0; kk < 16; ++kk) {
            float a[4], b[4];
#pragma unroll
            for (int i = 0; i < 4; ++i) a[i] = As[kk * 65 + ty * 4 + i];
#pragma unroll
            for (int j = 0; j < 4; ++j) b[j] = Bs[kk * 64 + tx * 4 + j];
#pragma unroll
            for (int i = 0; i < 4; ++i)
#pragma unroll
                for (int j = 0; j < 4; ++j) acc[i][j] = fmaf(a[i], b[j], acc[i][j]);
        }
        __syncthreads();
    }
#pragma unroll
    for (int i = 0; i < 4; ++i) {
        int gr = row0 + ty * 4 + i;
#pragma unroll
        for (int j = 0; j < 4; ++j) {
            int gc = col0 + tx * 4 + j;
            float vv = acc[i][j];
            if (bias) vv += bias[gc];
            if (ACT == 1) vv = fmaxf(vv, 0.f);
            if (ACT == 2) vv = 1.f / (1.f + expf(-vv));
            C[(size_t)gr * X + gc] = vv;
        }
    }
}

// ---------------------------------------------------------------------------
// K3: row GEMM for narrow outputs (X<=64): one block per row, 256 threads.
// blockIdx.y picks between two sets.
// ---------------------------------------------------------------------------
template<int ACT, int X>
__global__ void rowgemm_kernel(const float* __restrict__ A0, const float* __restrict__ B0,
                               const float* __restrict__ b0, float* __restrict__ C0,
                               const float* __restrict__ A1, const float* __restrict__ B1,
                               const float* __restrict__ b1, float* __restrict__ C1,
                               int K) {
    const float* A    = blockIdx.y ? A1 : A0;
    const float* Bm   = blockIdx.y ? B1 : B0;
    const float* bias = blockIdx.y ? b1 : b0;
    float*       C    = blockIdx.y ? C1 : C0;
    constexpr int SPLIT = 256 / X;
    int row = blockIdx.x;
    int col = threadIdx.x % X;
    int part = threadIdx.x / X;
    int kper = K / SPLIT;
    int ks = part * kper;
    float acc = 0.f;
    for (int k = ks; k < ks + kper; ++k)
        acc = fmaf(A[(size_t)row * K + k], Bm[(size_t)k * X + col], acc);
    __shared__ float red[256];
    red[threadIdx.x] = acc;
    __syncthreads();
    if (part == 0) {
        float v = acc;
#pragma unroll
        for (int p = 1; p < SPLIT; ++p) v += red[p * X + col];
        v += bias[col];
        if (ACT == 1) v = fmaxf(v, 0.f);
        if (ACT == 2) v = 1.f / (1.f + expf(-v));
        C[(size_t)row * X + col] = v;
    }
}

// ---------------------------------------------------------------------------
// K4: build compress-MLP inputs: cin[(h*W+w), p*DH+d] = k[h, w*BS+p, d] + k_pos[h,p,d]
// ---------------------------------------------------------------------------
__global__ void build_cmlp_in(const float* __restrict__ qkv, const float* __restrict__ k_pos,
                              const float* __restrict__ v_pos,
                              float* __restrict__ cin_k, float* __restrict__ cin_v) {
    int idx = blockIdx.x * 256 + threadIdx.x;   // 4*32*32*64 = 262144
    int d = idx & 63;
    int p = (idx >> 6) & 31;
    int w = (idx >> 11) & 31;
    int h = idx >> 16;
    int nn = w * BSZ + p;
    float kv = qkv[(size_t)nn * QKVD + (HEADS + h) * DH + d] + k_pos[(h * BSZ + p) * DH + d];
    float vv = qkv[(size_t)nn * QKVD + (HEADS + KVH + h) * DH + d] + v_pos[(h * BSZ + p) * DH + d];
    cin_k[idx] = kv;
    cin_v[idx] = vv;
}

// ---------------------------------------------------------------------------
// K5: assemble ck/cv = concat(mem_kv, mlp_out) : [KVH][MEM+W][DH]
// ---------------------------------------------------------------------------
__global__ void assemble_ckcv(const float* __restrict__ mem_kv, const float* __restrict__ ckp,
                              const float* __restrict__ cvp,
                              float* __restrict__ ck, float* __restrict__ cv) {
    int idx = blockIdx.x * 256 + threadIdx.x;   // 4*33*64 = 8448
    if (idx >= KVH * 33 * DH) return;
    int d = idx & 63;
    int j = (idx >> 6) % 33;
    int h = idx / (33 * 64);
    if (j == 0) {
        ck[idx] = mem_kv[(0 * KVH + h) * DH + d];
        cv[idx] = mem_kv[(1 * KVH + h) * DH + d];
    } else {
        ck[idx] = ckp[(h * WBLK + (j - 1)) * DH + d];
        cv[idx] = cvp[(h * WBLK + (j - 1)) * DH + d];
    }
}

// ---------------------------------------------------------------------------
// K6: interleaved rotary for q (16 heads) and k (4 heads)
// ---------------------------------------------------------------------------
__global__ void rotary_kernel(const float* __restrict__ qkv,
                              float* __restrict__ qr, float* __restrict__ kr) {
    int idx = blockIdx.x * 256 + threadIdx.x;   // 20*1024*32 = 655360
    int i = idx & 31;
    int n = (idx >> 5) & 1023;
    int hd = idx >> 15;
    if (hd >= HEADS + KVH) return;
    float inv = powf(10000.f, -(float)i / 32.f);
    float fr = (float)n * inv;
    float c = cosf(fr), s = sinf(fr);
    const float* src; float* dst;
    if (hd < HEADS) { src = qkv + (size_t)n * QKVD + hd * DH;          dst = qr + ((size_t)hd * NTOK + n) * DH; }
    else { int h = hd - HEADS;
           src = qkv + (size_t)n * QKVD + (HEADS + h) * DH;            dst = kr + ((size_t)h * NTOK + n) * DH; }
    float x0 = src[2 * i], x1 = src[2 * i + 1];
    dst[2 * i]     = x0 * c - x1 * s;
    dst[2 * i + 1] = x1 * c + x0 * s;
}

// ---------------------------------------------------------------------------
// K7: compressed attention + importance softmax + top-k selection.
// One 64-thread block per (n, h). Uses PRE-rotary q from qkv.
// ---------------------------------------------------------------------------
__global__ void cattn_kernel(const float* __restrict__ qkv, const float* __restrict__ ck,
                             const float* __restrict__ cv, float* __restrict__ c_out,
                             int* __restrict__ sel, int* __restrict__ selmask) {
    int n = blockIdx.x, h = blockIdx.y;
    int lane = threadIdx.x;          // 0..63, single wave
    __shared__ float cks[33 * 65];
    __shared__ float cvs[33 * 65];
    __shared__ float qs[4 * 64];
    __shared__ float sims[4 * 33];
    __shared__ float attn_s[64];

    for (int t = lane; t < 33 * 64; t += 64) {
        int j = t >> 6, d = t & 63;
        cks[j * 65 + d] = ck[(size_t)h * 33 * 64 + t];
        cvs[j * 65 + d] = cv[(size_t)h * 33 * 64 + t];
    }
#pragma unroll
    for (int g = 0; g < GQ; ++g)
        qs[g * 64 + lane] = qkv[(size_t)n * QKVD + (h * GQ + g) * DH + lane];
    __syncthreads();

    for (int g = 0; g < GQ; ++g) {
        float s = NEGINF;
        if (lane < 33) {
            float acc = 0.f;
#pragma unroll
            for (int d = 0; d < 64; ++d) acc = fmaf(qs[g * 64 + d], cks[lane * 65 + d], acc);
            s = acc * SCALE;
            sims[g * 33 + lane] = s;
        }
        float m = s;
        for (int off = 32; off; off >>= 1) m = fmaxf(m, __shfl_xor(m, off));
        float e = (lane < 33) ? expf(s - m) : 0.f;
        float sum = e;
        for (int off = 32; off; off >>= 1) sum += __shfl_xor(sum, off);
        attn_s[lane] = (lane < 33) ? e / sum : 0.f;
        __syncthreads();
        float acc2 = 0.f;
#pragma unroll
        for (int j = 0; j < 33; ++j) acc2 = fmaf(attn_s[j], cvs[j * 65 + lane], acc2);
        c_out[(((size_t)(h * GQ + g)) * NTOK + n) * DH + lane] = acc2;
        __syncthreads();
    }

    // importance = mean over g of scaled csim (blocks only), softmax over 32,
    // (the -1000 pad underflows to exactly 0 in f32, so plain softmax matches)
    float ival = NEGINF;
    if (lane < 32)
        ival = 0.25f * (sims[0 * 33 + 1 + lane] + sims[1 * 33 + 1 + lane] +
                        sims[2 * 33 + 1 + lane] + sims[3 * 33 + 1 + lane]);
    float m = ival;
    for (int off = 32; off; off >>= 1) m = fmaxf(m, __shfl_xor(m, off));
    float e = (lane < 32) ? expf(ival - m) : 0.f;
    float sum = e;
    for (int off = 32; off; off >>= 1) sum += __shfl_xor(sum, off);
    float p = (lane < 32) ? e / sum : NEGINF;

    // top-8, jax tie-break (equal values -> lower index first)
    float v = p;
    int base = (h * NTOK + n) * 9;
    for (int t = 0; t < NSEL; ++t) {
        float bv = v; int bi = lane;
        for (int off = 32; off; off >>= 1) {
            float ov = __shfl_xor(bv, off);
            int   oi = __shfl_xor(bi, off);
            if (ov > bv || (ov == bv && oi < bi)) { bv = ov; bi = oi; }
        }
        if (lane == 0) { sel[base + t] = bi; selmask[base + t] = (bv > 1e-10f) ? 1 : 0; }
        if (lane == bi) v = NEGINF;
    }
    if (lane == 0) { sel[base + NSEL] = n >> 5; selmask[base + NSEL] = 1; }
}

// ---------------------------------------------------------------------------
// K8: fine (selected-block) attention. One 256-thread block per (n, h).
// Uses rotary q/k, raw v (straight from qkv). 9 blocks x 32 keys = 288.
// ---------------------------------------------------------------------------
__global__ void fattn_kernel(const float* __restrict__ qr, const float* __restrict__ kr,
                             const float* __restrict__ qkv, const int* __restrict__ sel,
                             const int* __restrict__ selmask, float* __restrict__ f_out) {
    int n = blockIdx.x, h = blockIdx.y;
    int tid = threadIdx.x;           // 256
    __shared__ float qs[4 * 64];
    __shared__ float kvs[32 * 65];
    __shared__ float sims[4 * 288];
    __shared__ int sel_s[9], msk_s[9];

    if (tid < 9) {
        sel_s[tid] = sel[(h * NTOK + n) * 9 + tid];
        msk_s[tid] = selmask[(h * NTOK + n) * 9 + tid];
    }
    qs[tid] = qr[(((size_t)(h * GQ + (tid >> 6))) * NTOK + n) * DH + (tid & 63)];
    __syncthreads();

    // pass 1: scores
    for (int b = 0; b < 9; ++b) {
        int blk = sel_s[b];
        for (int t = tid; t < BSZ * DH; t += 256) {
            int j = t >> 6, d = t & 63;
            kvs[j * 65 + d] = kr[((size_t)h * NTOK + blk * BSZ + j) * DH + d];
        }
        __syncthreads();
        if (tid < 128) {
            int g = tid >> 5, j = tid & 31;
            float s;
            if (msk_s[b]) {
                float acc = 0.f;
#pragma unroll
                for (int d = 0; d < 64; ++d) acc = fmaf(qs[g * 64 + d], kvs[j * 65 + d], acc);
                s = acc * SCALE;
            } else s = -3.402823466e+38f;
            sims[g * 288 + b * 32 + j] = s;
        }
        __syncthreads();
    }

    // softmax over 288 per g (one wave per g)
    {
        int g = tid >> 6, lane = tid & 63;
        float m = NEGINF;
        for (int t = lane; t < 288; t += 64) m = fmaxf(m, sims[g * 288 + t]);
        for (int off = 32; off; off >>= 1) m = fmaxf(m, __shfl_xor(m, off));
        float ev[5];
        int cnt = 0;
        float sum = 0.f;
        for (int t = lane; t < 288; t += 64) { float ee = expf(sims[g * 288 + t] - m); ev[cnt++] = ee; sum += ee; }
        for (int off = 32; off; off >>= 1) sum += __shfl_xor(sum, off);
        float inv = 1.f / sum;
        cnt = 0;
        for (int t = lane; t < 288; t += 64) sims[g * 288 + t] = ev[cnt++] * inv;
    }
    __syncthreads();

    // pass 2: weighted V accumulate
    int g = tid >> 6, d = tid & 63;
    float acc = 0.f;
    for (int b = 0; b < 9; ++b) {
        int blk = sel_s[b];
        for (int t = tid; t < BSZ * DH; t += 256) {
            int j = t >> 6, dd = t & 63;
            kvs[j * 65 + dd] = qkv[((size_t)(blk * BSZ + j)) * QKVD + (HEADS + KVH + h) * DH + dd];
        }
        __syncthreads();
#pragma unroll
        for (int j = 0; j < 32; ++j) acc = fmaf(sims[g * 288 + b * 32 + j], kvs[j * 65 + d], acc);
        __syncthreads();
    }
    f_out[(((size_t)(h * GQ + g)) * NTOK + n) * DH + d] = acc;
}

// ---------------------------------------------------------------------------
// K9: gated mix -> (N, HEADS*DH)
// ---------------------------------------------------------------------------
__global__ void mix_kernel(const float* __restrict__ gates, const float* __restrict__ c_out,
                           const float* __restrict__ f_out, float* __restrict__ mix) {
    int idx = blockIdx.x * 256 + threadIdx.x;   // 1024*16*64
    int d = idx & 63;
    int hd = (idx >> 6) & 15;
    int n = idx >> 10;
    float g0 = gates[n * 32 + hd * 2];
    float g1 = gates[n * 32 + hd * 2 + 1];
    size_t hoff = (((size_t)hd) * NTOK + n) * DH + d;
    mix[(size_t)n * DDIM + hd * DH + d] = g0 * c_out[hoff] + g1 * f_out[hoff];
}

// ---------------------------------------------------------------------------
extern "C" void kernel_launch(void* const* d_in, const int* in_sizes, int n_in,
                              void* d_out, int out_size, void* d_ws, size_t ws_size,
                              hipStream_t stream) {
    const float* inp    = (const float*)d_in[0];
    const float* g_norm = (const float*)d_in[1];
    const float* w_qkv  = (const float*)d_in[2];
    const float* mem_kv = (const float*)d_in[3];
    const float* k_pos  = (const float*)d_in[4];
    const float* v_pos  = (const float*)d_in[5];
    const float* k_w1   = (const float*)d_in[6];
    const float* k_b1   = (const float*)d_in[7];
    const float* k_w2   = (const float*)d_in[8];
    const float* k_b2   = (const float*)d_in[9];
    const float* v_w1   = (const float*)d_in[10];
    const float* v_b1   = (const float*)d_in[11];
    const float* v_w2   = (const float*)d_in[12];
    const float* v_b2   = (const float*)d_in[13];
    const float* gate_w = (const float*)d_in[14];
    const float* gate_b = (const float*)d_in[15];
    const float* w_out  = (const float*)d_in[16];
    float* out = (float*)d_out;

    float* ws = (float*)d_ws;
    size_t o = 0;
    float* x     = ws + o; o += (size_t)NTOK * DDIM;          // 1M; later reused as 'mix'
    float* qkvb  = ws + o; o += (size_t)NTOK * QKVD;          // 1.5M
    float* cin_k = ws + o;                                    // 4 x 256K region, reused as qr
    float* cin_v = cin_k + 128 * CDIM;
    float* hid_k = cin_v + 128 * CDIM;
    float* hid_v = hid_k + 128 * HIDN;
    float* qr    = cin_k;                                     // overlays after MLP consumed
    o += 4 * (size_t)128 * 2048;                              // 1M
    float* kr    = ws + o; o += (size_t)KVH * NTOK * DH;      // 256K
    float* ckp   = ws + o; o += 128 * DH;
    float* cvp   = ws + o; o += 128 * DH;
    float* ck    = ws + o; o += KVH * 33 * DH;
    float* cv    = ws + o; o += KVH * 33 * DH;
    float* c_out = ws + o; o += (size_t)HEADS * NTOK * DH;    // 1M
    float* f_out = ws + o; o += (size_t)HEADS * NTOK * DH;    // 1M
    float* gates = ws + o; o += (size_t)NTOK * 32;
    int* sel     = (int*)(ws + o); o += (size_t)KVH * NTOK * 9;
    int* selmask = (int*)(ws + o); o += (size_t)KVH * NTOK * 9;
    float* mix   = x;

    // 1. RMSNorm
    rmsnorm_kernel<<<NTOK, 256, 0, stream>>>(inp, g_norm, x);
    // 2. qkv = x @ w_qkv
    gemm_kernel<0><<<dim3(QKVD / 64, NTOK / 64, 1), 256, 0, stream>>>(
        x, w_qkv, nullptr, qkvb, x, w_qkv, nullptr, qkvb, NTOK, DDIM, QKVD);
    // 3. gates = sigmoid(x @ gate_w + gate_b)
    rowgemm_kernel<2, 32><<<dim3(NTOK, 1), 256, 0, stream>>>(
        x, gate_w, gate_b, gates, x, gate_w, gate_b, gates, DDIM);
    // 4. compress-MLP inputs (k+pos, v+pos flattened per block)
    build_cmlp_in<<<(KVH * WBLK * BSZ * DH) / 256, 256, 0, stream>>>(qkvb, k_pos, v_pos, cin_k, cin_v);
    // 5. MLP layer 1 (relu), k & v batched over z
    gemm_kernel<1><<<dim3(HIDN / 64, 128 / 64, 2), 256, 0, stream>>>(
        cin_k, k_w1, k_b1, hid_k, cin_v, v_w1, v_b1, hid_v, 128, CDIM, HIDN);
    // 6. MLP layer 2, k & v batched over y
    rowgemm_kernel<0, 64><<<dim3(128, 2), 256, 0, stream>>>(
        hid_k, k_w2, k_b2, ckp, hid_v, v_w2, v_b2, cvp, HIDN);
    // 7. concat mem_kv
    assemble_ckcv<<<(KVH * 33 * DH + 255) / 256, 256, 0, stream>>>(mem_kv, ckp, cvp, ck, cv);
    // 8. rotary (overwrites cin/hid region with qr)
    rotary_kernel<<<((HEADS + KVH) * NTOK * 32) / 256, 256, 0, stream>>>(qkvb, qr, kr);
    // 9. compressed attention + selection
    cattn_kernel<<<dim3(NTOK, KVH), 64, 0, stream>>>(qkvb, ck, cv, c_out, sel, selmask);
    // 10. fine attention
    fattn_kernel<<<dim3(NTOK, KVH), 256, 0, stream>>>(qr, kr, qkvb, sel, selmask, f_out);
    // 11. gated mix
    mix_kernel<<<(NTOK * HEADS * DH) / 256, 256, 0, stream>>>(gates, c_out, f_out, mix);
    // 12. output projection
    gemm_kernel<0><<<dim3(DDIM / 64, NTOK / 64, 1), 256, 0, stream>>>(
        mix, w_out, nullptr, out, mix, w_out, nullptr, out, NTOK, DDIM, DDIM);
}

// Round 2
// 626.411 us; speedup vs baseline: 1.4345x; 1.4345x over previous
//
#include <hip/hip_runtime.h>
#include <math.h>

// ---- fixed problem sizes ----
#define NTOK 1024
#define DDIM 1024
#define HEADS 16
#define KVH 4
#define DH 64
#define BSZ 32
#define NSEL 8
#define WBLK 32            // NTOK / BSZ
#define GQ 4               // HEADS / KVH
#define CDIM 2048          // BSZ*DH
#define HIDN 2048
#define QKVD 1536          // (HEADS + 2*KVH)*DH
#define SCALE 0.125f       // DH^-0.5
#define NEGINF (-__builtin_inff())

typedef unsigned short u16;
typedef u16   u16x4  __attribute__((ext_vector_type(4)));
typedef u16   u16x8  __attribute__((ext_vector_type(8)));
typedef short short8 __attribute__((ext_vector_type(8)));
typedef float f32x4  __attribute__((ext_vector_type(4)));

__device__ __forceinline__ u16 f2bf(float f) {
    unsigned u = __float_as_uint(f);
    return (u16)((u + 0x7fffu + ((u >> 16) & 1u)) >> 16);
}
__device__ __forceinline__ float bf2f(u16 h) { return __uint_as_float(((unsigned)h) << 16); }

__device__ __forceinline__ void glds16(const void* g, void* l) {
    __builtin_amdgcn_global_load_lds(
        (const __attribute__((address_space(1))) unsigned int*)g,
        (__attribute__((address_space(3))) unsigned int*)l, 16, 0, 0);
}

// ---------------------------------------------------------------------------
// K1: RMSNorm -> x (f32) + split-bf16 copies (GEMM A operand)
// ---------------------------------------------------------------------------
__global__ void rmsnorm_kernel(const float* __restrict__ inp, const float* __restrict__ g,
                               float* __restrict__ x, u16* __restrict__ xhi, u16* __restrict__ xlo) {
    int n = blockIdx.x;
    int t = threadIdx.x;            // 256 threads, one float4 each
    float4 v = ((const float4*)(inp + (size_t)n * DDIM))[t];
    float ss = v.x*v.x + v.y*v.y + v.z*v.z + v.w*v.w;
    for (int off = 32; off; off >>= 1) ss += __shfl_down(ss, off);
    __shared__ float red[4];
    if ((t & 63) == 0) red[t >> 6] = ss;
    __syncthreads();
    float tot = red[0] + red[1] + red[2] + red[3];
    float r = 1.f / sqrtf(tot * (1.f / DDIM) + 1e-6f);
    float4 gv = ((const float4*)g)[t];
    float o[4];
    o[0] = v.x * r * gv.x; o[1] = v.y * r * gv.y;
    o[2] = v.z * r * gv.z; o[3] = v.w * r * gv.w;
    ((float4*)(x + (size_t)n * DDIM))[t] = *(float4*)o;
    u16x4 h, l;
#pragma unroll
    for (int i = 0; i < 4; ++i) {
        u16 hh = f2bf(o[i]);
        h[i] = hh;
        l[i] = f2bf(o[i] - bf2f(hh));
    }
    ((u16x4*)(xhi + (size_t)n * DDIM))[t] = h;
    ((u16x4*)(xlo + (size_t)n * DDIM))[t] = l;
}

// ---------------------------------------------------------------------------
// K2: weight transpose + split to bf16: W[K][N] f32 -> Thi/Tlo [N][K] bf16
// 64x64 tiles, 256 threads.
// ---------------------------------------------------------------------------
__global__ void transpose_split(const float* __restrict__ W, u16* __restrict__ Thi,
                                u16* __restrict__ Tlo, int K, int N) {
    __shared__ float tile[64][65];
    int k0 = blockIdx.y * 64, n0 = blockIdx.x * 64;
    int t = threadIdx.x;
    int r = t >> 4, c4 = (t & 15) * 4;
#pragma unroll
    for (int p = 0; p < 4; ++p) {
        float4 v = *(const float4*)&W[(size_t)(k0 + r + p * 16) * N + n0 + c4];
        tile[r + p * 16][c4 + 0] = v.x;
        tile[r + p * 16][c4 + 1] = v.y;
        tile[r + p * 16][c4 + 2] = v.z;
        tile[r + p * 16][c4 + 3] = v.w;
    }
    __syncthreads();
    int n = t >> 2, ks = (t & 3) * 16;
    u16x8 h0, h1, l0, l1;
#pragma unroll
    for (int kk = 0; kk < 16; ++kk) {
        float v = tile[ks + kk][n];
        u16 hh = f2bf(v);
        u16 ll = f2bf(v - bf2f(hh));
        if (kk < 8) { h0[kk] = hh; l0[kk] = ll; }
        else        { h1[kk - 8] = hh; l1[kk - 8] = ll; }
    }
    size_t ob = (size_t)(n0 + n) * K + k0 + ks;
    *(u16x8*)&Thi[ob] = h0;
    *(u16x8*)&Thi[ob + 8] = h1;
    if (Tlo) {
        *(u16x8*)&Tlo[ob] = l0;
        *(u16x8*)&Tlo[ob + 8] = l1;
    }
}

// ---------------------------------------------------------------------------
// K3: MFMA GEMM, C = act(A @ Bt^T + bias). A: [M][K] bf16 hi/lo, Bt: [N][K] bf16 hi/lo.
// 128x128 tile, 256 threads (4 waves), each wave 64x64 via 4x4 of 16x16x32 MFMA.
// SPLIT=3: acc += Ahi*Bhi + Ahi*Blo + Alo*Bhi (≈ f32 precision). SPLIT=1: bf16 only.
// LDS is kept in MFMA-fragment order: staged by global_load_lds with per-lane
// permuted global addresses; all fragment reads are lane-consecutive b128.
// ---------------------------------------------------------------------------
template<int SPLIT, int ACT>
__global__ __launch_bounds__(256, 1)
void gemm_mfma(const u16* __restrict__ Ahi0, const u16* __restrict__ Alo0,
               const u16* __restrict__ Bthi0, const u16* __restrict__ Btlo0,
               const float* __restrict__ bias0, float* __restrict__ C0,
               const u16* __restrict__ Ahi1, const u16* __restrict__ Alo1,
               const u16* __restrict__ Bthi1, const u16* __restrict__ Btlo1,
               const float* __restrict__ bias1, float* __restrict__ C1,
               int M, int N, int K) {
    const u16* Ahi  = blockIdx.z ? Ahi1  : Ahi0;
    const u16* Alo  = blockIdx.z ? Alo1  : Alo0;
    const u16* Bthi = blockIdx.z ? Bthi1 : Bthi0;
    const u16* Btlo = blockIdx.z ? Btlo1 : Btlo0;
    const float* bias = blockIdx.z ? bias1 : bias0;
    float* C = blockIdx.z ? C1 : C0;

    __shared__ u16 smA[2][8 * 64 * 8];   // [hi/lo][(group*64+lane)*8]
    __shared__ u16 smB[2][8 * 64 * 8];

    int tid = threadIdx.x;
    int w = tid >> 6, L = tid & 63;
    int m15 = L & 15, q = L >> 4;
    int rowbase = blockIdx.y * 128;
    int colbase = blockIdx.x * 128;

    // staging: wave w stages groups {2w, 2w+1} of each part
    const u16* pAh0 = Ahi + (size_t)(rowbase + (2 * w) * 16 + m15) * K + q * 8;
    const u16* pAh1 = pAh0 + (size_t)16 * K;
    const u16* pAl0 = Alo + (size_t)(rowbase + (2 * w) * 16 + m15) * K + q * 8;
    const u16* pAl1 = pAl0 + (size_t)16 * K;
    const u16* pBh0 = Bthi + (size_t)(colbase + (2 * w) * 16 + m15) * K + q * 8;
    const u16* pBh1 = pBh0 + (size_t)16 * K;
    const u16* pBl0 = Btlo + (size_t)(colbase + (2 * w) * 16 + m15) * K + q * 8;
    const u16* pBl1 = pBl0 + (size_t)16 * K;
    u16* dAh0 = &smA[0][(2 * w) * 64 * 8];
    u16* dAh1 = &smA[0][(2 * w + 1) * 64 * 8];
    u16* dAl0 = &smA[1][(2 * w) * 64 * 8];
    u16* dAl1 = &smA[1][(2 * w + 1) * 64 * 8];
    u16* dBh0 = &smB[0][(2 * w) * 64 * 8];
    u16* dBh1 = &smB[0][(2 * w + 1) * 64 * 8];
    u16* dBl0 = &smB[1][(2 * w) * 64 * 8];
    u16* dBl1 = &smB[1][(2 * w + 1) * 64 * 8];

    int aw = w & 1, bw = w >> 1;       // wave's A row group / B col group base
    f32x4 acc[4][4];
#pragma unroll
    for (int i = 0; i < 4; ++i)
#pragma unroll
        for (int j = 0; j < 4; ++j) acc[i][j] = (f32x4){0.f, 0.f, 0.f, 0.f};

    for (int k0 = 0; k0 < K; k0 += 32) {
        glds16(pAh0 + k0, dAh0);
        glds16(pAh1 + k0, dAh1);
        glds16(pBh0 + k0, dBh0);
        glds16(pBh1 + k0, dBh1);
        if constexpr (SPLIT == 3) {
            glds16(pAl0 + k0, dAl0);
            glds16(pAl1 + k0, dAl1);
            glds16(pBl0 + k0, dBl0);
            glds16(pBl1 + k0, dBl1);
        }
        __syncthreads();

        short8 ah[4], bh[4];
#pragma unroll
        for (int i = 0; i < 4; ++i) {
            ah[i] = *(const short8*)&smA[0][((aw * 4 + i) * 64 + L) * 8];
            bh[i] = *(const short8*)&smB[0][((bw * 4 + i) * 64 + L) * 8];
        }
        if constexpr (SPLIT == 3) {
            short8 al[4], bl[4];
#pragma unroll
            for (int i = 0; i < 4; ++i) {
                al[i] = *(const short8*)&smA[1][((aw * 4 + i) * 64 + L) * 8];
                bl[i] = *(const short8*)&smB[1][((bw * 4 + i) * 64 + L) * 8];
            }
#pragma unroll
            for (int i = 0; i < 4; ++i)
#pragma unroll
                for (int j = 0; j < 4; ++j) {
                    acc[i][j] = __builtin_amdgcn_mfma_f32_16x16x32_bf16(ah[i], bl[j], acc[i][j], 0, 0, 0);
                    acc[i][j] = __builtin_amdgcn_mfma_f32_16x16x32_bf16(al[i], bh[j], acc[i][j], 0, 0, 0);
                    acc[i][j] = __builtin_amdgcn_mfma_f32_16x16x32_bf16(ah[i], bh[j], acc[i][j], 0, 0, 0);
                }
        } else {
#pragma unroll
            for (int i = 0; i < 4; ++i)
#pragma unroll
                for (int j = 0; j < 4; ++j)
                    acc[i][j] = __builtin_amdgcn_mfma_f32_16x16x32_bf16(ah[i], bh[j], acc[i][j], 0, 0, 0);
        }
        __syncthreads();
    }

#pragma unroll
    for (int i = 0; i < 4; ++i) {
        int row = rowbase + aw * 64 + i * 16 + q * 4;
#pragma unroll
        for (int j = 0; j < 4; ++j) {
            int col = colbase + bw * 64 + j * 16 + m15;
            float bv = bias ? bias[col] : 0.f;
#pragma unroll
            for (int r = 0; r < 4; ++r) {
                float v = acc[i][j][r] + bv;
                if (ACT == 1) v = fmaxf(v, 0.f);
                C[(size_t)(row + r) * N + col] = v;
            }
        }
    }
}

// ---------------------------------------------------------------------------
// K4: row GEMM for narrow outputs (X<=64), f32 (kept for gates / MLP2)
// ---------------------------------------------------------------------------
template<int ACT, int X>
__global__ void rowgemm_kernel(const float* __restrict__ A0, const float* __restrict__ B0,
                               const float* __restrict__ b0, float* __restrict__ C0,
                               const float* __restrict__ A1, const float* __restrict__ B1,
                               const float* __restrict__ b1, float* __restrict__ C1,
                               int K) {
    const float* A    = blockIdx.y ? A1 : A0;
    const float* Bm   = blockIdx.y ? B1 : B0;
    const float* bias = blockIdx.y ? b1 : b0;
    float*       C    = blockIdx.y ? C1 : C0;
    constexpr int SPLIT = 256 / X;
    int row = blockIdx.x;
    int col = threadIdx.x % X;
    int part = threadIdx.x / X;
    int kper = K / SPLIT;
    int ks = part * kper;
    float acc = 0.f;
    for (int k = ks; k < ks + kper; ++k)
        acc = fmaf(A[(size_t)row * K + k], Bm[(size_t)k * X + col], acc);
    __shared__ float red[256];
    red[threadIdx.x] = acc;
    __syncthreads();
    if (part == 0) {
        float v = acc;
#pragma unroll
        for (int p = 1; p < SPLIT; ++p) v += red[p * X + col];
        v += bias[col];
        if (ACT == 1) v = fmaxf(v, 0.f);
        if (ACT == 2) v = 1.f / (1.f + expf(-v));
        C[(size_t)row * X + col] = v;
    }
}

// ---------------------------------------------------------------------------
// K5: build compress-MLP inputs, split-bf16 out
// ---------------------------------------------------------------------------
__global__ void build_cmlp_in(const float* __restrict__ qkv, const float* __restrict__ k_pos,
                              const float* __restrict__ v_pos,
                              u16* __restrict__ ckhi, u16* __restrict__ cklo,
                              u16* __restrict__ cvhi, u16* __restrict__ cvlo) {
    int idx = blockIdx.x * 256 + threadIdx.x;   // 4*32*32*64 = 262144
    int d = idx & 63;
    int p = (idx >> 6) & 31;
    int w = (idx >> 11) & 31;
    int h = idx >> 16;
    int nn = w * BSZ + p;
    float kv = qkv[(size_t)nn * QKVD + (HEADS + h) * DH + d] + k_pos[(h * BSZ + p) * DH + d];
    float vv = qkv[(size_t)nn * QKVD + (HEADS + KVH + h) * DH + d] + v_pos[(h * BSZ + p) * DH + d];
    u16 kh = f2bf(kv), vh = f2bf(vv);
    ckhi[idx] = kh; cklo[idx] = f2bf(kv - bf2f(kh));
    cvhi[idx] = vh; cvlo[idx] = f2bf(vv - bf2f(vh));
}

// ---------------------------------------------------------------------------
// K6: assemble ck/cv = concat(mem_kv, mlp_out) : [KVH][MEM+W][DH]
// ---------------------------------------------------------------------------
__global__ void assemble_ckcv(const float* __restrict__ mem_kv, const float* __restrict__ ckp,
                              const float* __restrict__ cvp,
                              float* __restrict__ ck, float* __restrict__ cv) {
    int idx = blockIdx.x * 256 + threadIdx.x;   // 4*33*64 = 8448
    if (idx >= KVH * 33 * DH) return;
    int d = idx & 63;
    int j = (idx >> 6) % 33;
    int h = idx / (33 * 64);
    if (j == 0) {
        ck[idx] = mem_kv[(0 * KVH + h) * DH + d];
        cv[idx] = mem_kv[(1 * KVH + h) * DH + d];
    } else {
        ck[idx] = ckp[(h * WBLK + (j - 1)) * DH + d];
        cv[idx] = cvp[(h * WBLK + (j - 1)) * DH + d];
    }
}

// ---------------------------------------------------------------------------
// K7: interleaved rotary for q (16 heads) and k (4 heads)
// ---------------------------------------------------------------------------
__global__ void rotary_kernel(const float* __restrict__ qkv,
                              float* __restrict__ qr, float* __restrict__ kr) {
    int idx = blockIdx.x * 256 + threadIdx.x;   // 20*1024*32 = 655360
    int i = idx & 31;
    int n = (idx >> 5) & 1023;
    int hd = idx >> 15;
    if (hd >= HEADS + KVH) return;
    float inv = powf(10000.f, -(float)i / 32.f);
    float fr = (float)n * inv;
    float c = cosf(fr), s = sinf(fr);
    const float* src; float* dst;
    if (hd < HEADS) { src = qkv + (size_t)n * QKVD + hd * DH;          dst = qr + ((size_t)hd * NTOK + n) * DH; }
    else { int h = hd - HEADS;
           src = qkv + (size_t)n * QKVD + (HEADS + h) * DH;            dst = kr + ((size_t)h * NTOK + n) * DH; }
    float x0 = src[2 * i], x1 = src[2 * i + 1];
    dst[2 * i]     = x0 * c - x1 * s;
    dst[2 * i + 1] = x1 * c + x0 * s;
}

// ---------------------------------------------------------------------------
// K8: compressed attention + importance softmax + top-k selection.
// ---------------------------------------------------------------------------
__global__ void cattn_kernel(const float* __restrict__ qkv, const float* __restrict__ ck,
                             const float* __restrict__ cv, float* __restrict__ c_out,
                             int* __restrict__ sel, int* __restrict__ selmask) {
    int n = blockIdx.x, h = blockIdx.y;
    int lane = threadIdx.x;          // 0..63, single wave
    __shared__ float cks[33 * 65];
    __shared__ float cvs[33 * 65];
    __shared__ float qs[4 * 64];
    __shared__ float sims[4 * 33];
    __shared__ float attn_s[64];

    for (int t = lane; t < 33 * 64; t += 64) {
        int j = t >> 6, d = t & 63;
        cks[j * 65 + d] = ck[(size_t)h * 33 * 64 + t];
        cvs[j * 65 + d] = cv[(size_t)h * 33 * 64 + t];
    }
#pragma unroll
    for (int g = 0; g < GQ; ++g)
        qs[g * 64 + lane] = qkv[(size_t)n * QKVD + (h * GQ + g) * DH + lane];
    __syncthreads();

    for (int g = 0; g < GQ; ++g) {
        float s = NEGINF;
        if (lane < 33) {
            float acc = 0.f;
#pragma unroll
            for (int d = 0; d < 64; ++d) acc = fmaf(qs[g * 64 + d], cks[lane * 65 + d], acc);
            s = acc * SCALE;
            sims[g * 33 + lane] = s;
        }
        float m = s;
        for (int off = 32; off; off >>= 1) m = fmaxf(m, __shfl_xor(m, off));
        float e = (lane < 33) ? expf(s - m) : 0.f;
        float sum = e;
        for (int off = 32; off; off >>= 1) sum += __shfl_xor(sum, off);
        attn_s[lane] = (lane < 33) ? e / sum : 0.f;
        __syncthreads();
        float acc2 = 0.f;
#pragma unroll
        for (int j = 0; j < 33; ++j) acc2 = fmaf(attn_s[j], cvs[j * 65 + lane], acc2);
        c_out[(((size_t)(h * GQ + g)) * NTOK + n) * DH + lane] = acc2;
        __syncthreads();
    }

    float ival = NEGINF;
    if (lane < 32)
        ival = 0.25f * (sims[0 * 33 + 1 + lane] + sims[1 * 33 + 1 + lane] +
                        sims[2 * 33 + 1 + lane] + sims[3 * 33 + 1 + lane]);
    float m = ival;
    for (int off = 32; off; off >>= 1) m = fmaxf(m, __shfl_xor(m, off));
    float e = (lane < 32) ? expf(ival - m) : 0.f;
    float sum = e;
    for (int off = 32; off; off >>= 1) sum += __shfl_xor(sum, off);
    float p = (lane < 32) ? e / sum : NEGINF;

    float v = p;
    int base = (h * NTOK + n) * 9;
    for (int t = 0; t < NSEL; ++t) {
        float bv = v; int bi = lane;
        for (int off = 32; off; off >>= 1) {
            float ov = __shfl_xor(bv, off);
            int   oi = __shfl_xor(bi, off);
            if (ov > bv || (ov == bv && oi < bi)) { bv = ov; bi = oi; }
        }
        if (lane == 0) { sel[base + t] = bi; selmask[base + t] = (bv > 1e-10f) ? 1 : 0; }
        if (lane == bi) v = NEGINF;
    }
    if (lane == 0) { sel[base + NSEL] = n >> 5; selmask[base + NSEL] = 1; }
}

// ---------------------------------------------------------------------------
// K9: fine (selected-block) attention.
// ---------------------------------------------------------------------------
__global__ void fattn_kernel(const float* __restrict__ qr, const float* __restrict__ kr,
                             const float* __restrict__ qkv, const int* __restrict__ sel,
                             const int* __restrict__ selmask, float* __restrict__ f_out) {
    int n = blockIdx.x, h = blockIdx.y;
    int tid = threadIdx.x;           // 256
    __shared__ float qs[4 * 64];
    __shared__ float kvs[32 * 65];
    __shared__ float sims[4 * 288];
    __shared__ int sel_s[9], msk_s[9];

    if (tid < 9) {
        sel_s[tid] = sel[(h * NTOK + n) * 9 + tid];
        msk_s[tid] = selmask[(h * NTOK + n) * 9 + tid];
    }
    qs[tid] = qr[(((size_t)(h * GQ + (tid >> 6))) * NTOK + n) * DH + (tid & 63)];
    __syncthreads();

    for (int b = 0; b < 9; ++b) {
        int blk = sel_s[b];
        for (int t = tid; t < BSZ * DH; t += 256) {
            int j = t >> 6, d = t & 63;
            kvs[j * 65 + d] = kr[((size_t)h * NTOK + blk * BSZ + j) * DH + d];
        }
        __syncthreads();
        if (tid < 128) {
            int g = tid >> 5, j = tid & 31;
            float s;
            if (msk_s[b]) {
                float acc = 0.f;
#pragma unroll
                for (int d = 0; d < 64; ++d) acc = fmaf(qs[g * 64 + d], kvs[j * 65 + d], acc);
                s = acc * SCALE;
            } else s = -3.402823466e+38f;
            sims[g * 288 + b * 32 + j] = s;
        }
        __syncthreads();
    }

    {
        int g = tid >> 6, lane = tid & 63;
        float m = NEGINF;
        for (int t = lane; t < 288; t += 64) m = fmaxf(m, sims[g * 288 + t]);
        for (int off = 32; off; off >>= 1) m = fmaxf(m, __shfl_xor(m, off));
        float ev[5];
        int cnt = 0;
        float sum = 0.f;
        for (int t = lane; t < 288; t += 64) { float ee = expf(sims[g * 288 + t] - m); ev[cnt++] = ee; sum += ee; }
        for (int off = 32; off; off >>= 1) sum += __shfl_xor(sum, off);
        float inv = 1.f / sum;
        cnt = 0;
        for (int t = lane; t < 288; t += 64) sims[g * 288 + t] = ev[cnt++] * inv;
    }
    __syncthreads();

    int g = tid >> 6, d = tid & 63;
    float acc = 0.f;
    for (int b = 0; b < 9; ++b) {
        int blk = sel_s[b];
        for (int t = tid; t < BSZ * DH; t += 256) {
            int j = t >> 6, dd = t & 63;
            kvs[j * 65 + dd] = qkv[((size_t)(blk * BSZ + j)) * QKVD + (HEADS + KVH + h) * DH + dd];
        }
        __syncthreads();
#pragma unroll
        for (int j = 0; j < 32; ++j) acc = fmaf(sims[g * 288 + b * 32 + j], kvs[j * 65 + d], acc);
        __syncthreads();
    }
    f_out[(((size_t)(h * GQ + g)) * NTOK + n) * DH + d] = acc;
}

// ---------------------------------------------------------------------------
// K10: gated mix -> split-bf16 (A operand of out-proj)
// ---------------------------------------------------------------------------
__global__ void mix_kernel(const float* __restrict__ gates, const float* __restrict__ c_out,
                           const float* __restrict__ f_out,
                           u16* __restrict__ mixhi, u16* __restrict__ mixlo) {
    int idx = blockIdx.x * 256 + threadIdx.x;   // 1024*16*64
    int d = idx & 63;
    int hd = (idx >> 6) & 15;
    int n = idx >> 10;
    float g0 = gates[n * 32 + hd * 2];
    float g1 = gates[n * 32 + hd * 2 + 1];
    size_t hoff = (((size_t)hd) * NTOK + n) * DH + d;
    float v = g0 * c_out[hoff] + g1 * f_out[hoff];
    u16 hh = f2bf(v);
    mixhi[(size_t)n * DDIM + hd * DH + d] = hh;
    mixlo[(size_t)n * DDIM + hd * DH + d] = f2bf(v - bf2f(hh));
}

// ---------------------------------------------------------------------------
extern "C" void kernel_launch(void* const* d_in, const int* in_sizes, int n_in,
                              void* d_out, int out_size, void* d_ws, size_t ws_size,
                              hipStream_t stream) {
    const float* inp    = (const float*)d_in[0];
    const float* g_norm = (const float*)d_in[1];
    const float* w_qkv  = (const float*)d_in[2];
    const float* mem_kv = (const float*)d_in[3];
    const float* k_pos  = (const float*)d_in[4];
    const float* v_pos  = (const float*)d_in[5];
    const float* k_w1   = (const float*)d_in[6];
    const float* k_b1   = (const float*)d_in[7];
    const float* k_w2   = (const float*)d_in[8];
    const float* k_b2   = (const float*)d_in[9];
    const float* v_w1   = (const float*)d_in[10];
    const float* v_b1   = (const float*)d_in[11];
    const float* v_w2   = (const float*)d_in[12];
    const float* v_b2   = (const float*)d_in[13];
    const float* gate_w = (const float*)d_in[14];
    const float* gate_b = (const float*)d_in[15];
    const float* w_out  = (const float*)d_in[16];
    float* out = (float*)d_out;

    char* wsb = (char*)d_ws;
    size_t off = 0;
    auto alloc = [&](size_t bytes) -> void* {
        void* p = wsb + off;
        off = (off + bytes + 255) & ~(size_t)255;
        return p;
    };
    float* x      = (float*)alloc((size_t)NTOK * DDIM * 4);
    u16*   xhi    = (u16*)  alloc((size_t)NTOK * DDIM * 2);
    u16*   xlo    = (u16*)  alloc((size_t)NTOK * DDIM * 2);
    float* qkvb   = (float*)alloc((size_t)NTOK * QKVD * 4);
    u16*   wqThi  = (u16*)  alloc((size_t)QKVD * DDIM * 2);
    u16*   wqTlo  = (u16*)  alloc((size_t)QKVD * DDIM * 2);
    u16*   kw1Thi = (u16*)  alloc((size_t)HIDN * CDIM * 2);
    u16*   kw1Tlo = (u16*)  alloc((size_t)HIDN * CDIM * 2);
    u16*   vw1Thi = (u16*)  alloc((size_t)HIDN * CDIM * 2);
    u16*   vw1Tlo = (u16*)  alloc((size_t)HIDN * CDIM * 2);
    u16*   woThi  = (u16*)  alloc((size_t)DDIM * DDIM * 2);
    u16*   cinkhi = (u16*)  alloc((size_t)128 * CDIM * 2);
    u16*   cinklo = (u16*)  alloc((size_t)128 * CDIM * 2);
    u16*   cinvhi = (u16*)  alloc((size_t)128 * CDIM * 2);
    u16*   cinvlo = (u16*)  alloc((size_t)128 * CDIM * 2);
    float* hidk   = (float*)alloc((size_t)128 * HIDN * 4);
    float* hidv   = (float*)alloc((size_t)128 * HIDN * 4);
    float* ckp    = (float*)alloc((size_t)128 * DH * 4);
    float* cvp    = (float*)alloc((size_t)128 * DH * 4);
    float* ck     = (float*)alloc((size_t)KVH * 33 * DH * 4);
    float* cv     = (float*)alloc((size_t)KVH * 33 * DH * 4);
    float* qr     = (float*)alloc((size_t)HEADS * NTOK * DH * 4);
    float* kr     = (float*)alloc((size_t)KVH * NTOK * DH * 4);
    float* c_out  = (float*)alloc((size_t)HEADS * NTOK * DH * 4);
    float* f_out  = (float*)alloc((size_t)HEADS * NTOK * DH * 4);
    float* gates  = (float*)alloc((size_t)NTOK * 32 * 4);
    int*   sel    = (int*)  alloc((size_t)KVH * NTOK * 9 * 4);
    int*   selmask= (int*)  alloc((size_t)KVH * NTOK * 9 * 4);
    u16*   mixhi  = (u16*)  alloc((size_t)NTOK * DDIM * 2);
    u16*   mixlo  = (u16*)  alloc((size_t)NTOK * DDIM * 2);

    // weight transposes + split (independent of activations)
    transpose_split<<<dim3(QKVD / 64, DDIM / 64), 256, 0, stream>>>(w_qkv, wqThi, wqTlo, DDIM, QKVD);
    transpose_split<<<dim3(HIDN / 64, CDIM / 64), 256, 0, stream>>>(k_w1, kw1Thi, kw1Tlo, CDIM, HIDN);
    transpose_split<<<dim3(HIDN / 64, CDIM / 64), 256, 0, stream>>>(v_w1, vw1Thi, vw1Tlo, CDIM, HIDN);
    transpose_split<<<dim3(DDIM / 64, DDIM / 64), 256, 0, stream>>>(w_out, woThi, nullptr, DDIM, DDIM);

    // 1. RMSNorm (+ split-bf16 x)
    rmsnorm_kernel<<<NTOK, 256, 0, stream>>>(inp, g_norm, x, xhi, xlo);
    // 2. qkv = x @ w_qkv   (split-bf16, ~f32 accurate)
    gemm_mfma<3, 0><<<dim3(QKVD / 128, NTOK / 128, 1), 256, 0, stream>>>(
        xhi, xlo, wqThi, wqTlo, nullptr, qkvb,
        xhi, xlo, wqThi, wqTlo, nullptr, qkvb, NTOK, QKVD, DDIM);
    // 3. gates = sigmoid(x @ gate_w + gate_b)
    rowgemm_kernel<2, 32><<<dim3(NTOK, 1), 256, 0, stream>>>(
        x, gate_w, gate_b, gates, x, gate_w, gate_b, gates, DDIM);
    // 4. compress-MLP inputs
    build_cmlp_in<<<(KVH * WBLK * BSZ * DH) / 256, 256, 0, stream>>>(
        qkvb, k_pos, v_pos, cinkhi, cinklo, cinvhi, cinvlo);
    // 5. MLP layer 1 (relu+bias), k & v batched over z
    gemm_mfma<3, 1><<<dim3(HIDN / 128, 1, 2), 256, 0, stream>>>(
        cinkhi, cinklo, kw1Thi, kw1Tlo, k_b1, hidk,
        cinvhi, cinvlo, vw1Thi, vw1Tlo, v_b1, hidv, 128, HIDN, CDIM);
    // 6. MLP layer 2
    rowgemm_kernel<0, 64><<<dim3(128, 2), 256, 0, stream>>>(
        hidk, k_w2, k_b2, ckp, hidv, v_w2, v_b2, cvp, HIDN);
    // 7. concat mem_kv
    assemble_ckcv<<<(KVH * 33 * DH + 255) / 256, 256, 0, stream>>>(mem_kv, ckp, cvp, ck, cv);
    // 8. rotary
    rotary_kernel<<<((HEADS + KVH) * NTOK * 32) / 256, 256, 0, stream>>>(qkvb, qr, kr);
    // 9. compressed attention + selection
    cattn_kernel<<<dim3(NTOK, KVH), 64, 0, stream>>>(qkvb, ck, cv, c_out, sel, selmask);
    // 10. fine attention
    fattn_kernel<<<dim3(NTOK, KVH), 256, 0, stream>>>(qr, kr, qkvb, sel, selmask, f_out);
    // 11. gated mix (-> bf16 hi/lo)
    mix_kernel<<<(NTOK * HEADS * DH) / 256, 256, 0, stream>>>(gates, c_out, f_out, mixhi, mixlo);
    // 12. output projection (plain bf16 is plenty here)
    gemm_mfma<1, 0><<<dim3(DDIM / 128, NTOK / 128, 1), 256, 0, stream>>>(
        mixhi, mixhi, woThi, woThi, nullptr, out,
        mixhi, mixhi, woThi, woThi, nullptr, out, NTOK, DDIM, DDIM);
}